// Round 7
// baseline (710.264 us; speedup 1.0000x reference)
//
#include <hip/hip_runtime.h>

#define DIM 64
#define NEG 0.2f
#define SB 1024
#define RPW 8    // rows per wave in proj3
#define SCH 4096 // edges per queue pop in scatter3x

__device__ __forceinline__ float rl(float v, int l) {
  return __int_as_float(__builtin_amdgcn_readlane(__float_as_int(v), l));
}

__device__ __forceinline__ unsigned short f2bf(float f) {  // fp32 -> bf16 RNE
  unsigned u = __float_as_uint(f);
  u += 0x7FFFu + ((u >> 16) & 1u);
  return (unsigned short)(u >> 16);
}

__device__ __forceinline__ int get_xcc() {  // physical XCD id [m09-verified]
  unsigned v;
  asm volatile("s_getreg_b32 %0, hwreg(HW_REG_XCC_ID)" : "=s"(v));
  return (int)(v & 7);
}

// ================= prep: q[b] = W_rel @ (al|ar)  [row-dot], bias = b0+b1+b2 =================
__global__ __launch_bounds__(64) void prep_kernel(
    const float* __restrict__ W0, const float* __restrict__ W1, const float* __restrict__ W2,
    const float* __restrict__ al0, const float* __restrict__ ar0,
    const float* __restrict__ al1, const float* __restrict__ ar1,
    const float* __restrict__ al2, const float* __restrict__ ar2,
    const float* __restrict__ b0, const float* __restrict__ b1, const float* __restrict__ b2,
    float* __restrict__ q, float* __restrict__ bias) {
  int b = blockIdx.x, c = threadIdx.x;
  if (b < 6) {
    int rel = b >> 1;
    const float* W = rel == 0 ? W0 : (rel == 1 ? W1 : W2);
    const float* a;
    if (b & 1) a = rel == 0 ? ar0 : (rel == 1 ? ar1 : ar2);
    else       a = rel == 0 ? al0 : (rel == 1 ? al1 : al2);
    float s = 0.f;
#pragma unroll
    for (int j = 0; j < DIM; ++j) s = fmaf(W[c * DIM + j], a[j], s);  // thread c: W row c . a
    q[b * DIM + c] = s;
  } else {
    bias[c] = b0[c] + b1[c] + b2[c];
  }
}

// ================= el/er for all 3 relations: one thread per row =========
__global__ __launch_bounds__(256) void elr_kernel(
    const float* __restrict__ x, const float* __restrict__ q,
    float* __restrict__ el, float* __restrict__ er, int n) {
  __shared__ float Qs[6 * DIM];
  for (int i = threadIdx.x; i < 6 * DIM; i += 256) Qs[i] = q[i];
  __syncthreads();
  int i = blockIdx.x * blockDim.x + threadIdx.x;
  if (i >= n) return;
  const float4* x4 = (const float4*)x;
  const float4* Q4 = (const float4*)Qs;
  float a[6] = {0.f, 0.f, 0.f, 0.f, 0.f, 0.f};
#pragma unroll 4
  for (int t = 0; t < 16; ++t) {
    float4 xv = x4[(size_t)i * 16 + t];
#pragma unroll
    for (int j = 0; j < 6; ++j) {
      float4 qv = Q4[j * 16 + t];
      a[j] = fmaf(xv.x, qv.x, a[j]);
      a[j] = fmaf(xv.y, qv.y, a[j]);
      a[j] = fmaf(xv.z, qv.z, a[j]);
      a[j] = fmaf(xv.w, qv.w, a[j]);
    }
  }
#pragma unroll
  for (int r = 0; r < 3; ++r) {
    el[(size_t)r * n + i] = a[2 * r];
    er[(size_t)r * n + i] = a[2 * r + 1];
  }
}

// ================= proj3: 8 rows/wave, readlane x-broadcast, bf16 output ====================
__global__ __launch_bounds__(256) void proj3(
    const float* __restrict__ x,
    const float* __restrict__ W0, const float* __restrict__ W1, const float* __restrict__ W2,
    unsigned short* __restrict__ feat, int n) {
  __shared__ float WsP[3 * 4096];  // [rel][k2:32][lane:64][2] k-pair packed (48 KB)
  const int lane = threadIdx.x & 63;
  const int wv = threadIdx.x >> 6;
  for (int i = threadIdx.x; i < DIM * DIM; i += 256) {
    int k = i >> 6, c = i & 63;
    int d = (k >> 1) * 128 + c * 2 + (k & 1);
    WsP[d] = W0[i];
    WsP[4096 + d] = W1[i];
    WsP[8192 + d] = W2[i];
  }
  __syncthreads();

  const int rowbase = (blockIdx.x * 4 + wv) * RPW;
  float xr[RPW];
#pragma unroll
  for (int r = 0; r < RPW; ++r) {
    int row = rowbase + r;
    row = row < n ? row : n - 1;
    xr[r] = x[(size_t)row * DIM + lane];
  }
  float a0[RPW], a1[RPW], a2[RPW];
#pragma unroll
  for (int r = 0; r < RPW; ++r) { a0[r] = 0.f; a1[r] = 0.f; a2[r] = 0.f; }

  const float2* Wp0 = (const float2*)WsP;
  const float2* Wp1 = (const float2*)(WsP + 4096);
  const float2* Wp2 = (const float2*)(WsP + 8192);
#pragma unroll 8
  for (int k2 = 0; k2 < 32; ++k2) {
    float2 w0 = Wp0[k2 * 64 + lane];
    float2 w1 = Wp1[k2 * 64 + lane];
    float2 w2 = Wp2[k2 * 64 + lane];
#pragma unroll
    for (int r = 0; r < RPW; ++r) {
      float xv0 = rl(xr[r], 2 * k2);
      float xv1 = rl(xr[r], 2 * k2 + 1);
      a0[r] = fmaf(xv1, w0.y, fmaf(xv0, w0.x, a0[r]));
      a1[r] = fmaf(xv1, w1.y, fmaf(xv0, w1.x, a1[r]));
      a2[r] = fmaf(xv1, w2.y, fmaf(xv0, w2.x, a2[r]));
    }
  }
#pragma unroll
  for (int r = 0; r < RPW; ++r) {
    int row = rowbase + r;
    if (row < n) {
      feat[(size_t)row * DIM + lane] = f2bf(a0[r]);
      feat[((size_t)n + row) * DIM + lane] = f2bf(a1[r]);
      feat[((size_t)2 * n + row) * DIM + lane] = f2bf(a2[r]);
    }
  }
}

// ---------------- lean-path kernels (fallback if ws too small) ----------------
__global__ __launch_bounds__(256) void proj_kernel(
    const float* __restrict__ x, const float* __restrict__ W,
    const float* __restrict__ al, const float* __restrict__ ar,
    unsigned short* __restrict__ feat, float* __restrict__ el, float* __restrict__ er, int n) {
  __shared__ float Ws[DIM][DIM];
  int tid = threadIdx.y * 64 + threadIdx.x;
  for (int i = tid; i < DIM * DIM; i += 256) Ws[i >> 6][i & 63] = W[i];
  __syncthreads();
  int row = blockIdx.x * 4 + threadIdx.y;
  if (row >= n) return;
  int lane = threadIdx.x;
  const float* xr = x + (size_t)row * DIM;
  float acc = 0.f;
#pragma unroll
  for (int k = 0; k < DIM; ++k) acc = fmaf(xr[k], Ws[k][lane], acc);
  feat[(size_t)row * DIM + lane] = f2bf(acc);
  float pl = acc * al[lane], pr = acc * ar[lane];
#pragma unroll
  for (int o = 32; o > 0; o >>= 1) {
    pl += __shfl_xor(pl, o, 64);
    pr += __shfl_xor(pr, o, 64);
  }
  if (lane == 0) { el[row] = pl; er[row] = pr; }
}

__global__ void init_out(float* __restrict__ out,
                         const float* __restrict__ b0, const float* __restrict__ b1,
                         const float* __restrict__ b2, int n) {
  int i = blockIdx.x * blockDim.x + threadIdx.x;
  if (i < n * DIM) {
    int c = i & (DIM - 1);
    out[i] = b0[c] + b1[c] + b2[c];
  }
}

// ================= CSR build ==============
__global__ void count3(const int* __restrict__ d0, const int* __restrict__ d1,
                       const int* __restrict__ d2, int e0, int e1, int e2,
                       int* __restrict__ cnt, int n) {
  int i = blockIdx.x * blockDim.x + threadIdx.x;
  int r, li;
  const int* dp;
  if (i < e0)                { r = 0; li = i;           dp = d0; }
  else if (i < e0 + e1)      { r = 1; li = i - e0;      dp = d1; }
  else if (i < e0 + e1 + e2) { r = 2; li = i - e0 - e1; dp = d2; }
  else return;
  atomicAdd(&cnt[r * n + dp[li]], 1);
}

__global__ __launch_bounds__(SB) void scan1(const int* __restrict__ cnt, int* __restrict__ off,
                                            int* __restrict__ bsum, int n) {
  __shared__ int sm[SB];
  int i = blockIdx.x * SB + threadIdx.x;
  int v = (i < n) ? cnt[i] : 0;
  sm[threadIdx.x] = v;
  __syncthreads();
  for (int o = 1; o < SB; o <<= 1) {
    int t = ((int)threadIdx.x >= o) ? sm[threadIdx.x - o] : 0;
    __syncthreads();
    sm[threadIdx.x] += t;
    __syncthreads();
  }
  if (i < n) off[i + 1] = sm[threadIdx.x];
  if (threadIdx.x == SB - 1) bsum[blockIdx.x] = sm[SB - 1];
}

__global__ __launch_bounds__(SB) void scan2(int* __restrict__ bsum, int nb) {
  __shared__ int sm[SB];
  int v = ((int)threadIdx.x < nb) ? bsum[threadIdx.x] : 0;
  sm[threadIdx.x] = v;
  __syncthreads();
  for (int o = 1; o < SB; o <<= 1) {
    int t = ((int)threadIdx.x >= o) ? sm[threadIdx.x - o] : 0;
    __syncthreads();
    sm[threadIdx.x] += t;
    __syncthreads();
  }
  if ((int)threadIdx.x < nb) bsum[threadIdx.x] = sm[threadIdx.x] - v;
}

__global__ __launch_bounds__(SB) void scan3(int* __restrict__ off, const int* __restrict__ bsum,
                                            int n) {
  int i = blockIdx.x * SB + threadIdx.x;
  if (i < n) off[i + 1] += bsum[blockIdx.x];
  if (i == 0) off[0] = 0;
}

// ======= scatter3x: physical-XCD-owned scatter with per-XCD chunk queues + stealing =======
// Block reads its real XCC_ID; queue q covers ALL edge chunks, processed for dst-slice q.
// A block drains its own XCD's queue first (writes land in its own L2, ~3MB window),
// then steals from other queues (correct under any dispatch placement, normally a no-op).
__global__ __launch_bounds__(256) void scatter3x(
    const int* __restrict__ s0, const int* __restrict__ d0,
    const int* __restrict__ s1, const int* __restrict__ d1,
    const int* __restrict__ s2, const int* __restrict__ d2,
    int e0, int e1, int e2,
    const float* __restrict__ el, const float* __restrict__ er,
    const int* __restrict__ off, int* __restrict__ cur, int* __restrict__ qh,
    int2* __restrict__ pairs, int n, int nchunks,
    int b1, int b2, int b3, int b4, int b5, int b6, int b7) {
  const int xcc = get_xcc();
  const int tot = e0 + e1 + e2;
  __shared__ int chunk_s;
  for (int qi = 0; qi < 8; ++qi) {
    const int myq = (xcc + qi) & 7;  // own queue first, then steal
    while (true) {
      __syncthreads();
      if (threadIdx.x == 0) chunk_s = atomicAdd(&qh[myq], 1);
      __syncthreads();
      const int c = chunk_s;
      if (c >= nchunks) break;
      for (int base = c * SCH; base < (c + 1) * SCH; base += 256) {
        int i = base + threadIdx.x;
        if (i >= tot) break;
        int r, li;
        const int *sp, *dp;
        if (i < e0)           { r = 0; li = i;           sp = s0; dp = d0; }
        else if (i < e0 + e1) { r = 1; li = i - e0;      sp = s1; dp = d1; }
        else                  { r = 2; li = i - e0 - e1; sp = s2; dp = d2; }
        int d = dp[li];
        int slice = (d >= b1) + (d >= b2) + (d >= b3) + (d >= b4) +
                    (d >= b5) + (d >= b6) + (d >= b7);
        if (slice != myq) continue;
        int sN = sp[li];
        int gi = r * n + d;
        float v = el[(size_t)r * n + sN] + er[gi];
        v = v > 0.f ? v : NEG * v;
        int p = atomicAdd(&cur[gi], 1);
        int2 pr;
        pr.x = sN;
        pr.y = __float_as_int(v);
        pairs[off[gi] + p] = pr;
      }
    }
  }
}

__global__ void scatter_pair(const int* __restrict__ src, const int* __restrict__ dst,
                             const float* __restrict__ el, const float* __restrict__ er,
                             const int* __restrict__ off_r, int* __restrict__ cur_r,
                             int2* __restrict__ pairs, int ebase, int e) {
  int i = blockIdx.x * blockDim.x + threadIdx.x;
  if (i < e) {
    int d = dst[i], sN = src[i];
    float v = el[sN] + er[d];
    v = v > 0.f ? v : NEG * v;
    int p = atomicAdd(&cur_r[d], 1);
    int2 pr;
    pr.x = sN;
    pr.y = __float_as_int(v);
    pairs[off_r[d] + p - ebase] = pr;
  }
}

// ================= per-node softmax + aggregation: half-wave per node, bf16 feat =========
// fu: bf16 feat rows as uint (2 cols per uint), row stride 32 uints
__device__ __forceinline__ float2 rel2(const unsigned* __restrict__ fu,
                                       const int2* __restrict__ pairs,
                                       int beg, int end, int hl, int sl) {
  float2 acc = make_float2(0.f, 0.f);
  int deg = end - beg;
  if (deg <= 0) return acc;
  const int lbase = hl << 5;
  float s;
  if (deg <= 32) {
    int2 pr = (sl < deg) ? pairs[beg + sl] : make_int2(0, 0xFF800000);  // pad = -inf
    float v = __int_as_float(pr.y);
    float m = v;
#pragma unroll
    for (int o = 16; o > 0; o >>= 1) m = fmaxf(m, __shfl_xor(m, o, 64));
    float a = (sl < deg) ? __expf(v - m) : 0.f;
    float t = a;
#pragma unroll
    for (int o = 16; o > 0; o >>= 1) t += __shfl_xor(t, o, 64);
    s = t;
    int j = 0, bulk = deg & ~3;
    for (; j < bulk; j += 4) {  // 4 independent gathers in flight
      int sn0 = __shfl(pr.x, lbase + j, 64);     float a0 = __shfl(a, lbase + j, 64);
      int sn1 = __shfl(pr.x, lbase + j + 1, 64); float a1 = __shfl(a, lbase + j + 1, 64);
      int sn2 = __shfl(pr.x, lbase + j + 2, 64); float a2 = __shfl(a, lbase + j + 2, 64);
      int sn3 = __shfl(pr.x, lbase + j + 3, 64); float a3 = __shfl(a, lbase + j + 3, 64);
      unsigned u0 = fu[((size_t)sn0 << 5) + sl];
      unsigned u1 = fu[((size_t)sn1 << 5) + sl];
      unsigned u2 = fu[((size_t)sn2 << 5) + sl];
      unsigned u3 = fu[((size_t)sn3 << 5) + sl];
      acc.x = fmaf(a0, __uint_as_float(u0 << 16), acc.x);
      acc.y = fmaf(a0, __uint_as_float(u0 & 0xFFFF0000u), acc.y);
      acc.x = fmaf(a1, __uint_as_float(u1 << 16), acc.x);
      acc.y = fmaf(a1, __uint_as_float(u1 & 0xFFFF0000u), acc.y);
      acc.x = fmaf(a2, __uint_as_float(u2 << 16), acc.x);
      acc.y = fmaf(a2, __uint_as_float(u2 & 0xFFFF0000u), acc.y);
      acc.x = fmaf(a3, __uint_as_float(u3 << 16), acc.x);
      acc.y = fmaf(a3, __uint_as_float(u3 & 0xFFFF0000u), acc.y);
    }
    for (; j < deg; ++j) {
      int sn = __shfl(pr.x, lbase + j, 64);
      float aj = __shfl(a, lbase + j, 64);
      unsigned u = fu[((size_t)sn << 5) + sl];
      acc.x = fmaf(aj, __uint_as_float(u << 16), acc.x);
      acc.y = fmaf(aj, __uint_as_float(u & 0xFFFF0000u), acc.y);
    }
  } else {
    float m = -3.4e38f;
    for (int i = beg + sl; i < end; i += 32) m = fmaxf(m, __int_as_float(pairs[i].y));
#pragma unroll
    for (int o = 16; o > 0; o >>= 1) m = fmaxf(m, __shfl_xor(m, o, 64));
    s = 0.f;
    for (int base = beg; base < end; base += 32) {
      int cm = min(32, end - base);
      int2 pr = (sl < cm) ? pairs[base + sl] : make_int2(0, 0);
      float a = (sl < cm) ? __expf(__int_as_float(pr.y) - m) : 0.f;
      float t = a;
#pragma unroll
      for (int o = 16; o > 0; o >>= 1) t += __shfl_xor(t, o, 64);
      s += t;
      for (int j = 0; j < cm; ++j) {
        int sn = __shfl(pr.x, lbase + j, 64);
        float aj = __shfl(a, lbase + j, 64);
        unsigned u = fu[((size_t)sn << 5) + sl];
        acc.x = fmaf(aj, __uint_as_float(u << 16), acc.x);
        acc.y = fmaf(aj, __uint_as_float(u & 0xFFFF0000u), acc.y);
      }
    }
  }
  acc.x /= s;
  acc.y /= s;
  return acc;
}

__global__ __launch_bounds__(256) void agg3(
    const unsigned* __restrict__ fu, const int* __restrict__ off,
    const int2* __restrict__ pairs, const float* __restrict__ bias,
    float* __restrict__ out, int n) {
  int wave = (blockIdx.x * blockDim.x + threadIdx.x) >> 6;
  int lane = threadIdx.x & 63;
  int hl = lane >> 5, sl = lane & 31;
  int node = (wave << 1) + hl;
  if (node >= n) return;
  int o0b = off[node],         o0e = off[node + 1];
  int o1b = off[n + node],     o1e = off[n + node + 1];
  int o2b = off[2 * n + node], o2e = off[2 * n + node + 1];
  int c0 = sl << 1;
  float2 r = *(const float2*)(bias + c0);
  float2 c;
  c = rel2(fu, pairs, o0b, o0e, hl, sl);
  r.x += c.x; r.y += c.y;
  c = rel2(fu + (size_t)n * 32, pairs, o1b, o1e, hl, sl);
  r.x += c.x; r.y += c.y;
  c = rel2(fu + (size_t)2 * n * 32, pairs, o2b, o2e, hl, sl);
  r.x += c.x; r.y += c.y;
  *(float2*)(out + ((size_t)node << 6) + c0) = r;
}

__global__ __launch_bounds__(256) void agg1(
    const unsigned* __restrict__ fu, const int* __restrict__ off_r,
    const int2* __restrict__ pairs, int ebase, float* __restrict__ out, int n) {
  int wave = (blockIdx.x * blockDim.x + threadIdx.x) >> 6;
  int lane = threadIdx.x & 63;
  int hl = lane >> 5, sl = lane & 31;
  int node = (wave << 1) + hl;
  if (node >= n) return;
  float2 c = rel2(fu, pairs, off_r[node] - ebase, off_r[node + 1] - ebase, hl, sl);
  float* op = out + ((size_t)node << 6) + (sl << 1);
  op[0] += c.x;
  op[1] += c.y;
}

static inline char* alignup(char* p) {
  return (char*)(((uintptr_t)p + 255) & ~(uintptr_t)255);
}

extern "C" void kernel_launch(void* const* d_in, const int* in_sizes, int n_in,
                              void* d_out, int out_size, void* d_ws, size_t ws_size,
                              hipStream_t stream) {
  const float* x = (const float*)d_in[0];
  const int n = in_sizes[0] / DIM;
  const int m = 3 * n;
  float* out = (float*)d_out;

  const int eN[3] = {in_sizes[1], in_sizes[7], in_sizes[13]};
  const int eTot = eN[0] + eN[1] + eN[2];

  const size_t featB = (size_t)n * DIM * sizeof(unsigned short);  // bf16 feat
  const size_t nB = (size_t)n * sizeof(float);

  const size_t needFused = 3 * featB + 6 * nB + (2 * (size_t)m + 16) * 4 +
                           (size_t)(m + 2) * 4 + SB * 4 + 448 * 4 +
                           (size_t)eTot * 8 + 32 * 256;
  const bool fused = ws_size >= needFused;

  char* w = (char*)d_ws;
  unsigned short* feat = (unsigned short*)w;
  w += fused ? 3 * featB : featB;                    w = alignup(w);
  float* el = (float*)w;    w += fused ? 3 * nB : nB;  w = alignup(w);
  float* er = (float*)w;    w += fused ? 3 * nB : nB;  w = alignup(w);
  int* cnt = (int*)w;       w += (size_t)m * 4;      // cnt+cur+qh contiguous (one memset)
  int* cur = (int*)w;       w += (size_t)m * 4;
  int* qh  = (int*)w;       w += 16 * 4;              w = alignup(w);
  int* off = (int*)w;       w += (size_t)(m + 1) * 4; w = alignup(w);
  int* bsum = (int*)w;      w += SB * 4;              w = alignup(w);
  float* qbuf = (float*)w;  w += 384 * 4;             // 6 x 64 q-vectors
  float* bias = (float*)w;  w += 64 * 4;              w = alignup(w);
  int2* pairs = (int2*)w;

  const int nb = (m + SB - 1) / SB;  // 293 for n=100000 (scan2 handles nb<=1024)

  hipMemsetAsync(cnt, 0, (2 * (size_t)m + 16) * sizeof(int), stream);  // cnt+cur+qh
  count3<<<(eTot + 255) / 256, 256, 0, stream>>>(
      (const int*)d_in[2], (const int*)d_in[8], (const int*)d_in[14],
      eN[0], eN[1], eN[2], cnt, n);
  scan1<<<nb, SB, 0, stream>>>(cnt, off, bsum, m);
  scan2<<<1, SB, 0, stream>>>(bsum, nb);
  scan3<<<nb, SB, 0, stream>>>(off, bsum, m);

  if (fused) {
    prep_kernel<<<7, 64, 0, stream>>>(
        (const float*)d_in[3], (const float*)d_in[9], (const float*)d_in[15],
        (const float*)d_in[4], (const float*)d_in[5],
        (const float*)d_in[10], (const float*)d_in[11],
        (const float*)d_in[16], (const float*)d_in[17],
        (const float*)d_in[6], (const float*)d_in[12], (const float*)d_in[18],
        qbuf, bias);
    elr_kernel<<<(n + 255) / 256, 256, 0, stream>>>(x, qbuf, el, er, n);
    proj3<<<(n + 4 * RPW - 1) / (4 * RPW), 256, 0, stream>>>(
        x, (const float*)d_in[3], (const float*)d_in[9], (const float*)d_in[15], feat, n);
    // balanced contiguous dst slices: slice s = [n*s/8, n*(s+1)/8)
    int bd[8];
    for (int s = 0; s < 8; ++s) bd[s] = (int)(((long long)n * s) / 8);
    const int nchunks = (eTot + SCH - 1) / SCH;
    scatter3x<<<2048, 256, 0, stream>>>(
        (const int*)d_in[1], (const int*)d_in[2], (const int*)d_in[7], (const int*)d_in[8],
        (const int*)d_in[13], (const int*)d_in[14], eN[0], eN[1], eN[2],
        el, er, off, cur, qh, pairs, n, nchunks,
        bd[1], bd[2], bd[3], bd[4], bd[5], bd[6], bd[7]);
    agg3<<<(n + 7) / 8, 256, 0, stream>>>((const unsigned*)feat, off, pairs, bias, out, n);
  } else {
    init_out<<<(n * DIM + 255) / 256, 256, 0, stream>>>(
        out, (const float*)d_in[6], (const float*)d_in[12], (const float*)d_in[18], n);
    int ebase = 0;
    for (int r = 0; r < 3; ++r) {
      const int base = 1 + r * 6;
      proj_kernel<<<(n + 3) / 4, dim3(64, 4), 0, stream>>>(
          x, (const float*)d_in[base + 2], (const float*)d_in[base + 3],
          (const float*)d_in[base + 4], feat, el, er, n);
      scatter_pair<<<(eN[r] + 255) / 256, 256, 0, stream>>>(
          (const int*)d_in[base], (const int*)d_in[base + 1], el, er, off + (size_t)r * n,
          cur + (size_t)r * n, pairs, ebase, eN[r]);
      agg1<<<(n + 7) / 8, 256, 0, stream>>>((const unsigned*)feat, off + (size_t)r * n,
                                            pairs, ebase, out, n);
      ebase += eN[r];
    }
  }
}

// Round 9
// 611.566 us; speedup vs baseline: 1.1614x; 1.1614x over previous
//
#include <hip/hip_runtime.h>

#define DIM 64
#define NEG 0.2f
#define SB 1024
#define RPW 8      // rows per wave in proj3
#define BNODES 512 // gi per bucket
#define SHIFTB 9
#define NBMAX 1024
#define CHUNK 8192 // edges per WG in bin3

__device__ __forceinline__ float rl(float v, int l) {
  return __int_as_float(__builtin_amdgcn_readlane(__float_as_int(v), l));
}

__device__ __forceinline__ unsigned short f2bf(float f) {  // fp32 -> bf16 RNE
  unsigned u = __float_as_uint(f);
  u += 0x7FFFu + ((u >> 16) & 1u);
  return (unsigned short)(u >> 16);
}

// ================= prep: q[b] = W_rel @ (al|ar)  [row-dot], bias = b0+b1+b2 =================
__global__ __launch_bounds__(64) void prep_kernel(
    const float* __restrict__ W0, const float* __restrict__ W1, const float* __restrict__ W2,
    const float* __restrict__ al0, const float* __restrict__ ar0,
    const float* __restrict__ al1, const float* __restrict__ ar1,
    const float* __restrict__ al2, const float* __restrict__ ar2,
    const float* __restrict__ b0, const float* __restrict__ b1, const float* __restrict__ b2,
    float* __restrict__ q, float* __restrict__ bias) {
  int b = blockIdx.x, c = threadIdx.x;
  if (b < 6) {
    int rel = b >> 1;
    const float* W = rel == 0 ? W0 : (rel == 1 ? W1 : W2);
    const float* a;
    if (b & 1) a = rel == 0 ? ar0 : (rel == 1 ? ar1 : ar2);
    else       a = rel == 0 ? al0 : (rel == 1 ? al1 : al2);
    float s = 0.f;
#pragma unroll
    for (int j = 0; j < DIM; ++j) s = fmaf(W[c * DIM + j], a[j], s);  // thread c: W row c . a
    q[b * DIM + c] = s;
  } else {
    bias[c] = b0[c] + b1[c] + b2[c];
  }
}

// ================= el/er for all 3 relations: one thread per row =========
__global__ __launch_bounds__(256) void elr_kernel(
    const float* __restrict__ x, const float* __restrict__ q,
    float* __restrict__ el, float* __restrict__ er, int n) {
  __shared__ float Qs[6 * DIM];
  for (int i = threadIdx.x; i < 6 * DIM; i += 256) Qs[i] = q[i];
  __syncthreads();
  int i = blockIdx.x * blockDim.x + threadIdx.x;
  if (i >= n) return;
  const float4* x4 = (const float4*)x;
  const float4* Q4 = (const float4*)Qs;
  float a[6] = {0.f, 0.f, 0.f, 0.f, 0.f, 0.f};
#pragma unroll 4
  for (int t = 0; t < 16; ++t) {
    float4 xv = x4[(size_t)i * 16 + t];
#pragma unroll
    for (int j = 0; j < 6; ++j) {
      float4 qv = Q4[j * 16 + t];
      a[j] = fmaf(xv.x, qv.x, a[j]);
      a[j] = fmaf(xv.y, qv.y, a[j]);
      a[j] = fmaf(xv.z, qv.z, a[j]);
      a[j] = fmaf(xv.w, qv.w, a[j]);
    }
  }
#pragma unroll
  for (int r = 0; r < 3; ++r) {
    el[(size_t)r * n + i] = a[2 * r];
    er[(size_t)r * n + i] = a[2 * r + 1];
  }
}

// ================= proj3: 8 rows/wave, readlane x-broadcast, bf16 output ====================
__global__ __launch_bounds__(256) void proj3(
    const float* __restrict__ x,
    const float* __restrict__ W0, const float* __restrict__ W1, const float* __restrict__ W2,
    unsigned short* __restrict__ feat, int n) {
  __shared__ float WsP[3 * 4096];  // [rel][k2:32][lane:64][2] k-pair packed (48 KB)
  const int lane = threadIdx.x & 63;
  const int wv = threadIdx.x >> 6;
  for (int i = threadIdx.x; i < DIM * DIM; i += 256) {
    int k = i >> 6, c = i & 63;
    int d = (k >> 1) * 128 + c * 2 + (k & 1);
    WsP[d] = W0[i];
    WsP[4096 + d] = W1[i];
    WsP[8192 + d] = W2[i];
  }
  __syncthreads();

  const int rowbase = (blockIdx.x * 4 + wv) * RPW;
  float xr[RPW];
#pragma unroll
  for (int r = 0; r < RPW; ++r) {
    int row = rowbase + r;
    row = row < n ? row : n - 1;
    xr[r] = x[(size_t)row * DIM + lane];
  }
  float a0[RPW], a1[RPW], a2[RPW];
#pragma unroll
  for (int r = 0; r < RPW; ++r) { a0[r] = 0.f; a1[r] = 0.f; a2[r] = 0.f; }

  const float2* Wp0 = (const float2*)WsP;
  const float2* Wp1 = (const float2*)(WsP + 4096);
  const float2* Wp2 = (const float2*)(WsP + 8192);
#pragma unroll 8
  for (int k2 = 0; k2 < 32; ++k2) {
    float2 w0 = Wp0[k2 * 64 + lane];
    float2 w1 = Wp1[k2 * 64 + lane];
    float2 w2 = Wp2[k2 * 64 + lane];
#pragma unroll
    for (int r = 0; r < RPW; ++r) {
      float xv0 = rl(xr[r], 2 * k2);
      float xv1 = rl(xr[r], 2 * k2 + 1);
      a0[r] = fmaf(xv1, w0.y, fmaf(xv0, w0.x, a0[r]));
      a1[r] = fmaf(xv1, w1.y, fmaf(xv0, w1.x, a1[r]));
      a2[r] = fmaf(xv1, w2.y, fmaf(xv0, w2.x, a2[r]));
    }
  }
#pragma unroll
  for (int r = 0; r < RPW; ++r) {
    int row = rowbase + r;
    if (row < n) {
      feat[(size_t)row * DIM + lane] = f2bf(a0[r]);
      feat[((size_t)n + row) * DIM + lane] = f2bf(a1[r]);
      feat[((size_t)2 * n + row) * DIM + lane] = f2bf(a2[r]);
    }
  }
}

// ---------------- lean-path kernels (fallback if ws too small) ----------------
__global__ __launch_bounds__(256) void proj_kernel(
    const float* __restrict__ x, const float* __restrict__ W,
    const float* __restrict__ al, const float* __restrict__ ar,
    unsigned short* __restrict__ feat, float* __restrict__ el, float* __restrict__ er, int n) {
  __shared__ float Ws[DIM][DIM];
  int tid = threadIdx.y * 64 + threadIdx.x;
  for (int i = tid; i < DIM * DIM; i += 256) Ws[i >> 6][i & 63] = W[i];
  __syncthreads();
  int row = blockIdx.x * 4 + threadIdx.y;
  if (row >= n) return;
  int lane = threadIdx.x;
  const float* xr = x + (size_t)row * DIM;
  float acc = 0.f;
#pragma unroll
  for (int k = 0; k < DIM; ++k) acc = fmaf(xr[k], Ws[k][lane], acc);
  feat[(size_t)row * DIM + lane] = f2bf(acc);
  float pl = acc * al[lane], pr = acc * ar[lane];
#pragma unroll
  for (int o = 32; o > 0; o >>= 1) {
    pl += __shfl_xor(pl, o, 64);
    pr += __shfl_xor(pr, o, 64);
  }
  if (lane == 0) { el[row] = pl; er[row] = pr; }
}

__global__ void init_out(float* __restrict__ out,
                         const float* __restrict__ b0, const float* __restrict__ b1,
                         const float* __restrict__ b2, int n) {
  int i = blockIdx.x * blockDim.x + threadIdx.x;
  if (i < n * DIM) {
    int c = i & (DIM - 1);
    out[i] = b0[c] + b1[c] + b2[c];
  }
}

// ================= CSR build ==============
__global__ void count3(const int* __restrict__ d0, const int* __restrict__ d1,
                       const int* __restrict__ d2, int e0, int e1, int e2,
                       int* __restrict__ cnt, int n) {
  int i = blockIdx.x * blockDim.x + threadIdx.x;
  int r, li;
  const int* dp;
  if (i < e0)                { r = 0; li = i;           dp = d0; }
  else if (i < e0 + e1)      { r = 1; li = i - e0;      dp = d1; }
  else if (i < e0 + e1 + e2) { r = 2; li = i - e0 - e1; dp = d2; }
  else return;
  atomicAdd(&cnt[r * n + dp[li]], 1);
}

__global__ __launch_bounds__(SB) void scan1(const int* __restrict__ cnt, int* __restrict__ off,
                                            int* __restrict__ bsum, int n) {
  __shared__ int sm[SB];
  int i = blockIdx.x * SB + threadIdx.x;
  int v = (i < n) ? cnt[i] : 0;
  sm[threadIdx.x] = v;
  __syncthreads();
  for (int o = 1; o < SB; o <<= 1) {
    int t = ((int)threadIdx.x >= o) ? sm[threadIdx.x - o] : 0;
    __syncthreads();
    sm[threadIdx.x] += t;
    __syncthreads();
  }
  if (i < n) off[i + 1] = sm[threadIdx.x];
  if (threadIdx.x == SB - 1) bsum[blockIdx.x] = sm[SB - 1];
}

__global__ __launch_bounds__(SB) void scan2(int* __restrict__ bsum, int nb) {
  __shared__ int sm[SB];
  int v = ((int)threadIdx.x < nb) ? bsum[threadIdx.x] : 0;
  sm[threadIdx.x] = v;
  __syncthreads();
  for (int o = 1; o < SB; o <<= 1) {
    int t = ((int)threadIdx.x >= o) ? sm[threadIdx.x - o] : 0;
    __syncthreads();
    sm[threadIdx.x] += t;
    __syncthreads();
  }
  if ((int)threadIdx.x < nb) bsum[threadIdx.x] = sm[threadIdx.x] - v;
}

__global__ __launch_bounds__(SB) void scan3(int* __restrict__ off, const int* __restrict__ bsum,
                                            int n) {
  int i = blockIdx.x * SB + threadIdx.x;
  if (i < n) off[i + 1] += bsum[blockIdx.x];
  if (i == 0) off[0] = 0;
}

__global__ void init_bcur(const int* __restrict__ off, int* __restrict__ bcur, int nbuckets) {
  int b = blockIdx.x * blockDim.x + threadIdx.x;
  if (b < nbuckets) bcur[b] = off[b << SHIFTB];
}

// ======= bin3: counting-sort pass 1 — bin edges by dst-bucket in ARRIVAL order =======
// Sequential runs per (WG,bucket) -> streaming writes, no line re-dirtying.
__global__ __launch_bounds__(256) void bin3(
    const int* __restrict__ s0, const int* __restrict__ d0,
    const int* __restrict__ s1, const int* __restrict__ d1,
    const int* __restrict__ s2, const int* __restrict__ d2,
    int e0, int e1, int e2,
    const float* __restrict__ el, const float* __restrict__ er,
    int* __restrict__ bcur, int2* __restrict__ binPairs,
    unsigned short* __restrict__ binLoc, int n, int nbuckets) {
  __shared__ int hist[NBMAX];
  __shared__ int base[NBMAX];
  const int tot = e0 + e1 + e2;
  const int cbeg = blockIdx.x * CHUNK;
  const int cend = min(cbeg + CHUNK, tot);
  for (int b = threadIdx.x; b < nbuckets; b += 256) hist[b] = 0;
  __syncthreads();
  // phase a: LDS histogram of this chunk
  for (int i = cbeg + threadIdx.x; i < cend; i += 256) {
    int r, li;
    const int* dp;
    if (i < e0)           { r = 0; li = i;           dp = d0; }
    else if (i < e0 + e1) { r = 1; li = i - e0;      dp = d1; }
    else                  { r = 2; li = i - e0 - e1; dp = d2; }
    atomicAdd(&hist[(r * n + dp[li]) >> SHIFTB], 1);
  }
  __syncthreads();
  // phase b: one global reservation per non-empty bucket
  for (int b = threadIdx.x; b < nbuckets; b += 256) {
    int h = hist[b];
    base[b] = h ? atomicAdd(&bcur[b], h) : 0;
    hist[b] = 0;  // reuse as local cursor
  }
  __syncthreads();
  // phase c: compute logit, write to reserved run
  for (int i = cbeg + threadIdx.x; i < cend; i += 256) {
    int r, li;
    const int *sp, *dp;
    if (i < e0)           { r = 0; li = i;           sp = s0; dp = d0; }
    else if (i < e0 + e1) { r = 1; li = i - e0;      sp = s1; dp = d1; }
    else                  { r = 2; li = i - e0 - e1; sp = s2; dp = d2; }
    int d = dp[li], sN = sp[li];
    int gi = r * n + d;
    int b = gi >> SHIFTB;
    float v = el[(size_t)r * n + sN] + er[gi];
    v = v > 0.f ? v : NEG * v;
    int slot = atomicAdd(&hist[b], 1);
    int idx = base[b] + slot;
    int2 pr;
    pr.x = sN;
    pr.y = __float_as_int(v);
    binPairs[idx] = pr;
    binLoc[idx] = (unsigned short)(gi - (b << SHIFTB));
  }
}

// ======= place: pass 2 — one WG per bucket, scatter within a 41KB L2-resident window =======
__global__ __launch_bounds__(256) void place(
    const int* __restrict__ off, const int2* __restrict__ binPairs,
    const unsigned short* __restrict__ binLoc, int* __restrict__ cur,
    int2* __restrict__ pairs, int m) {
  const int b = blockIdx.x;
  const int gbeg = b << SHIFTB;
  const int gend = min(gbeg + BNODES, m);
  const int beg = off[gbeg], end = off[gend];
  for (int i = beg + threadIdx.x; i < end; i += 256) {
    int2 pr = binPairs[i];
    int gi = gbeg + (int)binLoc[i];
    int p = atomicAdd(&cur[gi], 1);
    pairs[off[gi] + p] = pr;
  }
}

__global__ void scatter_pair(const int* __restrict__ src, const int* __restrict__ dst,
                             const float* __restrict__ el, const float* __restrict__ er,
                             const int* __restrict__ off_r, int* __restrict__ cur_r,
                             int2* __restrict__ pairs, int ebase, int e) {
  int i = blockIdx.x * blockDim.x + threadIdx.x;
  if (i < e) {
    int d = dst[i], sN = src[i];
    float v = el[sN] + er[d];
    v = v > 0.f ? v : NEG * v;
    int p = atomicAdd(&cur_r[d], 1);
    int2 pr;
    pr.x = sN;
    pr.y = __float_as_int(v);
    pairs[off_r[d] + p - ebase] = pr;
  }
}

// ================= per-node softmax + aggregation: half-wave per node, bf16 feat =========
__device__ __forceinline__ float2 rel2(const unsigned* __restrict__ fu,
                                       const int2* __restrict__ pairs,
                                       int beg, int end, int hl, int sl) {
  float2 acc = make_float2(0.f, 0.f);
  int deg = end - beg;
  if (deg <= 0) return acc;
  const int lbase = hl << 5;
  float s;
  if (deg <= 32) {
    int2 pr = (sl < deg) ? pairs[beg + sl] : make_int2(0, 0xFF800000);  // pad = -inf
    float v = __int_as_float(pr.y);
    float m = v;
#pragma unroll
    for (int o = 16; o > 0; o >>= 1) m = fmaxf(m, __shfl_xor(m, o, 64));
    float a = (sl < deg) ? __expf(v - m) : 0.f;
    float t = a;
#pragma unroll
    for (int o = 16; o > 0; o >>= 1) t += __shfl_xor(t, o, 64);
    s = t;
    int j = 0, bulk = deg & ~3;
    for (; j < bulk; j += 4) {  // 4 independent gathers in flight
      int sn0 = __shfl(pr.x, lbase + j, 64);     float a0 = __shfl(a, lbase + j, 64);
      int sn1 = __shfl(pr.x, lbase + j + 1, 64); float a1 = __shfl(a, lbase + j + 1, 64);
      int sn2 = __shfl(pr.x, lbase + j + 2, 64); float a2 = __shfl(a, lbase + j + 2, 64);
      int sn3 = __shfl(pr.x, lbase + j + 3, 64); float a3 = __shfl(a, lbase + j + 3, 64);
      unsigned u0 = fu[((size_t)sn0 << 5) + sl];
      unsigned u1 = fu[((size_t)sn1 << 5) + sl];
      unsigned u2 = fu[((size_t)sn2 << 5) + sl];
      unsigned u3 = fu[((size_t)sn3 << 5) + sl];
      acc.x = fmaf(a0, __uint_as_float(u0 << 16), acc.x);
      acc.y = fmaf(a0, __uint_as_float(u0 & 0xFFFF0000u), acc.y);
      acc.x = fmaf(a1, __uint_as_float(u1 << 16), acc.x);
      acc.y = fmaf(a1, __uint_as_float(u1 & 0xFFFF0000u), acc.y);
      acc.x = fmaf(a2, __uint_as_float(u2 << 16), acc.x);
      acc.y = fmaf(a2, __uint_as_float(u2 & 0xFFFF0000u), acc.y);
      acc.x = fmaf(a3, __uint_as_float(u3 << 16), acc.x);
      acc.y = fmaf(a3, __uint_as_float(u3 & 0xFFFF0000u), acc.y);
    }
    for (; j < deg; ++j) {
      int sn = __shfl(pr.x, lbase + j, 64);
      float aj = __shfl(a, lbase + j, 64);
      unsigned u = fu[((size_t)sn << 5) + sl];
      acc.x = fmaf(aj, __uint_as_float(u << 16), acc.x);
      acc.y = fmaf(aj, __uint_as_float(u & 0xFFFF0000u), acc.y);
    }
  } else {
    float m = -3.4e38f;
    for (int i = beg + sl; i < end; i += 32) m = fmaxf(m, __int_as_float(pairs[i].y));
#pragma unroll
    for (int o = 16; o > 0; o >>= 1) m = fmaxf(m, __shfl_xor(m, o, 64));
    s = 0.f;
    for (int base = beg; base < end; base += 32) {
      int cm = min(32, end - base);
      int2 pr = (sl < cm) ? pairs[base + sl] : make_int2(0, 0);
      float a = (sl < cm) ? __expf(__int_as_float(pr.y) - m) : 0.f;
      float t = a;
#pragma unroll
      for (int o = 16; o > 0; o >>= 1) t += __shfl_xor(t, o, 64);
      s += t;
      for (int j = 0; j < cm; ++j) {
        int sn = __shfl(pr.x, lbase + j, 64);
        float aj = __shfl(a, lbase + j, 64);
        unsigned u = fu[((size_t)sn << 5) + sl];
        acc.x = fmaf(aj, __uint_as_float(u << 16), acc.x);
        acc.y = fmaf(aj, __uint_as_float(u & 0xFFFF0000u), acc.y);
      }
    }
  }
  acc.x /= s;
  acc.y /= s;
  return acc;
}

__global__ __launch_bounds__(256) void agg3(
    const unsigned* __restrict__ fu, const int* __restrict__ off,
    const int2* __restrict__ pairs, const float* __restrict__ bias,
    float* __restrict__ out, int n) {
  int wave = (blockIdx.x * blockDim.x + threadIdx.x) >> 6;
  int lane = threadIdx.x & 63;
  int hl = lane >> 5, sl = lane & 31;
  int node = (wave << 1) + hl;
  if (node >= n) return;
  int o0b = off[node],         o0e = off[node + 1];
  int o1b = off[n + node],     o1e = off[n + node + 1];
  int o2b = off[2 * n + node], o2e = off[2 * n + node + 1];
  int c0 = sl << 1;
  float2 r = *(const float2*)(bias + c0);
  float2 c;
  c = rel2(fu, pairs, o0b, o0e, hl, sl);
  r.x += c.x; r.y += c.y;
  c = rel2(fu + (size_t)n * 32, pairs, o1b, o1e, hl, sl);
  r.x += c.x; r.y += c.y;
  c = rel2(fu + (size_t)2 * n * 32, pairs, o2b, o2e, hl, sl);
  r.x += c.x; r.y += c.y;
  *(float2*)(out + ((size_t)node << 6) + c0) = r;
}

__global__ __launch_bounds__(256) void agg1(
    const unsigned* __restrict__ fu, const int* __restrict__ off_r,
    const int2* __restrict__ pairs, int ebase, float* __restrict__ out, int n) {
  int wave = (blockIdx.x * blockDim.x + threadIdx.x) >> 6;
  int lane = threadIdx.x & 63;
  int hl = lane >> 5, sl = lane & 31;
  int node = (wave << 1) + hl;
  if (node >= n) return;
  float2 c = rel2(fu, pairs, off_r[node] - ebase, off_r[node + 1] - ebase, hl, sl);
  float* op = out + ((size_t)node << 6) + (sl << 1);
  op[0] += c.x;
  op[1] += c.y;
}

static inline char* alignup(char* p) {
  return (char*)(((uintptr_t)p + 255) & ~(uintptr_t)255);
}

extern "C" void kernel_launch(void* const* d_in, const int* in_sizes, int n_in,
                              void* d_out, int out_size, void* d_ws, size_t ws_size,
                              hipStream_t stream) {
  const float* x = (const float*)d_in[0];
  const int n = in_sizes[0] / DIM;
  const int m = 3 * n;
  float* out = (float*)d_out;

  const int eN[3] = {in_sizes[1], in_sizes[7], in_sizes[13]};
  const int eTot = eN[0] + eN[1] + eN[2];
  const int nbuckets = (m + BNODES - 1) >> SHIFTB;  // 586 for n=100000

  const size_t featB = (size_t)n * DIM * sizeof(unsigned short);  // bf16 feat
  const size_t nB = (size_t)n * sizeof(float);

  const size_t needFused = 3 * featB + 6 * nB + 2 * (size_t)m * 4 + (size_t)(m + 2) * 4 +
                           SB * 4 + 448 * 4 + NBMAX * 4 + (size_t)eTot * 8 +
                           (size_t)eTot * 8 + (size_t)eTot * 2 + 64 * 256;
  const bool fused = (ws_size >= needFused) && (nbuckets <= NBMAX);

  char* w = (char*)d_ws;
  unsigned short* feat = (unsigned short*)w;
  w += fused ? 3 * featB : featB;                      w = alignup(w);
  float* el = (float*)w;    w += fused ? 3 * nB : nB;  w = alignup(w);
  float* er = (float*)w;    w += fused ? 3 * nB : nB;  w = alignup(w);
  int* cnt = (int*)w;       w += (size_t)m * 4;        // cnt+cur contiguous (one memset)
  int* cur = (int*)w;       w += (size_t)m * 4;        w = alignup(w);
  int* off = (int*)w;       w += (size_t)(m + 1) * 4;  w = alignup(w);
  int* bsum = (int*)w;      w += SB * 4;               w = alignup(w);
  float* qbuf = (float*)w;  w += 384 * 4;              // 6 x 64 q-vectors
  float* bias = (float*)w;  w += 64 * 4;               w = alignup(w);
  int* bcur = (int*)w;      w += NBMAX * 4;            w = alignup(w);
  int2* pairs = (int2*)w;   w += (size_t)eTot * 8;     w = alignup(w);
  int2* binPairs = (int2*)w; w += (size_t)eTot * 8;    w = alignup(w);
  unsigned short* binLoc = (unsigned short*)w;

  const int nb = (m + SB - 1) / SB;  // 293 for n=100000 (scan2 handles nb<=1024)

  hipMemsetAsync(cnt, 0, (size_t)2 * m * sizeof(int), stream);  // cnt + cur
  count3<<<(eTot + 255) / 256, 256, 0, stream>>>(
      (const int*)d_in[2], (const int*)d_in[8], (const int*)d_in[14],
      eN[0], eN[1], eN[2], cnt, n);
  scan1<<<nb, SB, 0, stream>>>(cnt, off, bsum, m);
  scan2<<<1, SB, 0, stream>>>(bsum, nb);
  scan3<<<nb, SB, 0, stream>>>(off, bsum, m);

  if (fused) {
    prep_kernel<<<7, 64, 0, stream>>>(
        (const float*)d_in[3], (const float*)d_in[9], (const float*)d_in[15],
        (const float*)d_in[4], (const float*)d_in[5],
        (const float*)d_in[10], (const float*)d_in[11],
        (const float*)d_in[16], (const float*)d_in[17],
        (const float*)d_in[6], (const float*)d_in[12], (const float*)d_in[18],
        qbuf, bias);
    elr_kernel<<<(n + 255) / 256, 256, 0, stream>>>(x, qbuf, el, er, n);
    proj3<<<(n + 4 * RPW - 1) / (4 * RPW), 256, 0, stream>>>(
        x, (const float*)d_in[3], (const float*)d_in[9], (const float*)d_in[15], feat, n);
    init_bcur<<<(nbuckets + 255) / 256, 256, 0, stream>>>(off, bcur, nbuckets);
    bin3<<<(eTot + CHUNK - 1) / CHUNK, 256, 0, stream>>>(
        (const int*)d_in[1], (const int*)d_in[2], (const int*)d_in[7], (const int*)d_in[8],
        (const int*)d_in[13], (const int*)d_in[14], eN[0], eN[1], eN[2],
        el, er, bcur, binPairs, binLoc, n, nbuckets);
    place<<<nbuckets, 256, 0, stream>>>(off, binPairs, binLoc, cur, pairs, m);
    agg3<<<(n + 7) / 8, 256, 0, stream>>>((const unsigned*)feat, off, pairs, bias, out, n);
  } else {
    init_out<<<(n * DIM + 255) / 256, 256, 0, stream>>>(
        out, (const float*)d_in[6], (const float*)d_in[12], (const float*)d_in[18], n);
    int ebase = 0;
    for (int r = 0; r < 3; ++r) {
      const int base = 1 + r * 6;
      proj_kernel<<<(n + 3) / 4, dim3(64, 4), 0, stream>>>(
          x, (const float*)d_in[base + 2], (const float*)d_in[base + 3],
          (const float*)d_in[base + 4], feat, el, er, n);
      scatter_pair<<<(eN[r] + 255) / 256, 256, 0, stream>>>(
          (const int*)d_in[base], (const int*)d_in[base + 1], el, er, off + (size_t)r * n,
          cur + (size_t)r * n, pairs, ebase, eN[r]);
      agg1<<<(n + 7) / 8, 256, 0, stream>>>((const unsigned*)feat, off + (size_t)r * n,
                                            pairs, ebase, out, n);
      ebase += eN[r];
    }
  }
}